// Round 4
// baseline (676.030 us; speedup 1.0000x reference)
//
#include <hip/hip_runtime.h>

#define TOPK    32
#define ROW     32768
#define THREADS 512
#define WAVES   8
#define VPT     16     // float4 per thread: 16 * 4 * 512 = 32768
#define BINS    2048
#define CAP     2048
#define BLOCKS  256    // 1 block per CU, persistent over rows/BLOCKS rows

__device__ __forceinline__ unsigned int f2key(float f) {
    // monotone map: larger float -> larger uint
    unsigned int u = __float_as_uint(f);
    return u ^ (0x80000000u | (unsigned int)((int)u >> 31));
}
__device__ __forceinline__ float key2f(unsigned int k) {
    unsigned int u = (k & 0x80000000u) ? (k & 0x7fffffffu) : ~k;
    return __uint_as_float(u);
}

// Raw barrier: LDS-ordering only. Deliberately does NOT drain vmcnt, so the
// next-row register prefetch stays in flight across select-phase barriers.
__device__ __forceinline__ void bar_lds() {
    asm volatile("s_waitcnt lgkmcnt(0)" ::: "memory");
    __builtin_amdgcn_s_barrier();
}

struct Shared {
    unsigned int hist[BINS];
    unsigned int wsum[WAVES];
    unsigned int sel_g, sel_gabove;
    unsigned int sel_bin, sel_above;
    unsigned int cand_cnt;
    unsigned int cnt_s;
    float        Tf;
    unsigned int idxcut;
    float        cf[CAP];
    unsigned int cidx[CAP];
};

// Find bin B = max index with sum_{b>=B} hist[b] >= kk.
// Writes sh.sel_bin (=B) and sh.sel_above (= sum over bins > B).
// Requires: total hist sum >= kk. Ends with a barrier.
__device__ __forceinline__ void hist_select(Shared& sh, int t, int lane,
                                            int wave, unsigned int kk) {
    // stage 1: wave w owns bins [w*256, w*256+256), 4 bins/lane
    const int base = wave * 256 + lane * 4;
    unsigned int h0 = sh.hist[base + 0], h1 = sh.hist[base + 1];
    unsigned int h2 = sh.hist[base + 2], h3 = sh.hist[base + 3];
    unsigned int p = h0 + h1 + h2 + h3;
    unsigned int s = p;  // suffix-inclusive sum over lanes >= lane
#pragma unroll
    for (int off = 1; off < 64; off <<= 1) {
        unsigned int vv = __shfl_down(s, off);
        if (lane + off < 64) s += vv;
    }
    if (lane == 0) sh.wsum[wave] = s;  // wave total
    bar_lds();

    // stage 2: find the wave-group containing the crossing
    if (t == 0) {
        unsigned int above = 0; int g = WAVES - 1;
        for (int w = WAVES - 1; w >= 0; --w) {
            if (above + sh.wsum[w] >= kk) { g = w; break; }
            above += sh.wsum[w];
        }
        sh.sel_g = (unsigned int)g; sh.sel_gabove = above;
    }
    bar_lds();

    // stage 3: the owning wave (still holds h0..h3, p, s) finds the bin
    if (wave == (int)sh.sel_g) {
        unsigned int a = sh.sel_gabove + (s - p);  // count in bins above my chunk
        unsigned int hh[4] = {h0, h1, h2, h3};
#pragma unroll
        for (int j = 3; j >= 0; --j) {
            unsigned int h = hh[j];
            if (a < kk && a + h >= kk) {
                sh.sel_bin = (unsigned int)(base + j);
                sh.sel_above = a;
            }
            a += h;
        }
    }
    bar_lds();
}

__device__ __forceinline__ void process_row(Shared& sh, const float4 (&v)[VPT],
                                            float* __restrict__ orow,
                                            int t, int lane, int wave) {
    // zero hist + counters (LDS only; ordered by bar_lds below)
#pragma unroll
    for (int b = 0; b < 4; ++b) sh.hist[t + b * THREADS] = 0;
    if (t == 0) sh.cand_cnt = 0;

    // per-thread max (pure VALU; waits only on this bank's loads)
    float m = -__builtin_inff();
#pragma unroll
    for (int i = 0; i < VPT; ++i)
        m = fmaxf(m, fmaxf(fmaxf(v[i].x, v[i].y), fmaxf(v[i].z, v[i].w)));

    bar_lds();
    // histogram of the 512 thread-maxima only (512 LDS atomics)
    atomicAdd(&sh.hist[f2key(m) >> 21], 1u);
    bar_lds();

    hist_select(sh, t, lane, wave, TOPK);

    // L = lower edge of the crossing bin. The top-32 thread-maxima are 32
    // distinct elements >= L, hence the true 32nd-largest >= L, hence the
    // candidate set {x >= L} contains the full top-32 (and C >= 32).
    const float L = key2f(sh.sel_bin << 21);

    // gather candidates
#pragma unroll
    for (int i = 0; i < VPT; ++i) {
#pragma unroll
        for (int j = 0; j < 4; ++j) {
            float f = (&v[i].x)[j];
            if (f >= L) {
                unsigned int pos = atomicAdd(&sh.cand_cnt, 1u);
                if (pos < CAP) {
                    sh.cf[pos]   = f;
                    sh.cidx[pos] = (unsigned int)((i * THREADS + t) * 4 + j);
                }
            }
        }
    }
    bar_lds();
    const unsigned int C = sh.cand_cnt;

    if (C <= CAP) {
        // exact rank among candidates: order = (value desc, idx asc)
        for (unsigned int i = t; i < C; i += THREADS) {
            float ki = sh.cf[i]; unsigned int ii = sh.cidx[i];
            unsigned int r = 0;
            for (unsigned int j = 0; j < C; ++j) {
                float kj = sh.cf[j];
                unsigned int ij = sh.cidx[j];
                r += (kj > ki || (kj == ki && ij < ii)) ? 1u : 0u;
            }
            if (r == TOPK - 1) { sh.Tf = ki; sh.idxcut = ii; }
        }
        bar_lds();
        const float T = sh.Tf;
        const unsigned int ic = sh.idxcut;
        float4* __restrict__ xout = reinterpret_cast<float4*>(orow);
#pragma unroll
        for (int i = 0; i < VPT; ++i) {
            float4 o;
#pragma unroll
            for (int j = 0; j < 4; ++j) {
                float f = (&v[i].x)[j];
                unsigned int idx = (unsigned int)((i * THREADS + t) * 4 + j);
                (&o.x)[j] = (f > T || (f == T && idx <= ic)) ? f : 0.0f;
            }
            xout[i * THREADS + t] = o;
        }
        return;
    }

    // ---- fallback (candidate overflow, adversarial data): exact radix select ----
    unsigned int prefix = 0; int pbits = 0;
    unsigned int kk = TOPK, e = 0;
    for (int r = 0; r < 3; ++r) {
        const int shift = (r == 0) ? 21 : (r == 1 ? 10 : 0);
        const int bits  = (r == 2) ? 10 : 11;
        const unsigned int msk = (1u << bits) - 1u;
        bar_lds();  // protect prior hist reads before re-zeroing
#pragma unroll
        for (int b = 0; b < 4; ++b) sh.hist[t + b * THREADS] = 0;
        bar_lds();
#pragma unroll
        for (int i = 0; i < VPT; ++i) {
#pragma unroll
            for (int j = 0; j < 4; ++j) {
                unsigned int key = f2key((&v[i].x)[j]);
                bool match = (pbits == 0) || ((key >> (32 - pbits)) == prefix);
                if (match) atomicAdd(&sh.hist[(key >> shift) & msk], 1u);
            }
        }
        bar_lds();
        hist_select(sh, t, lane, wave, kk);
        kk = kk - sh.sel_above;
        e  = sh.hist[sh.sel_bin];
        prefix = (prefix << bits) | sh.sel_bin;
        pbits += bits;
    }
    const unsigned int T = prefix;

    unsigned int Cc = ROW;  // idx cutoff for equal keys
    if (e != kk) {
        unsigned int lo = 0, hi = ROW;
        while (hi - lo > 1u) {
            unsigned int mid = (lo + hi) >> 1;
            bar_lds();
            if (t == 0) sh.cnt_s = 0;
            bar_lds();
            unsigned int c = 0;
#pragma unroll
            for (int i = 0; i < VPT; ++i) {
#pragma unroll
                for (int j = 0; j < 4; ++j) {
                    unsigned int key = f2key((&v[i].x)[j]);
                    unsigned int idx = (unsigned int)((i * THREADS + t) * 4 + j);
                    if (key == T && idx < mid) ++c;
                }
            }
            if (c) atomicAdd(&sh.cnt_s, c);
            bar_lds();
            if (sh.cnt_s >= kk) hi = mid; else lo = mid;
        }
        Cc = hi;
    }

    float4* __restrict__ xout = reinterpret_cast<float4*>(orow);
#pragma unroll
    for (int i = 0; i < VPT; ++i) {
        float4 o;
#pragma unroll
        for (int j = 0; j < 4; ++j) {
            float f = (&v[i].x)[j];
            unsigned int key = f2key(f);
            unsigned int idx = (unsigned int)((i * THREADS + t) * 4 + j);
            (&o.x)[j] = (key > T || (key == T && idx < Cc)) ? f : 0.0f;
        }
        xout[i * THREADS + t] = o;
    }
}

__global__ __launch_bounds__(THREADS, 2) void topk_pipelined_kernel(
    const float* __restrict__ x, float* __restrict__ out, int rpb) {

    __shared__ Shared sh;
    const int t    = threadIdx.x;
    const int lane = t & 63;
    const int wave = t >> 6;
    const int row0 = blockIdx.x * rpb;

    float4 vA[VPT], vB[VPT];

    // prologue: load first row into bank A
    {
        const float4* __restrict__ xin =
            reinterpret_cast<const float4*>(x + (size_t)row0 * ROW);
#pragma unroll
        for (int i = 0; i < VPT; ++i) vA[i] = xin[i * THREADS + t];
    }

    for (int r = 0; r < rpb; r += 2) {
        // prefetch row r+1 into bank B, then process bank A (row r)
        if (r + 1 < rpb) {
            const float4* __restrict__ xin =
                reinterpret_cast<const float4*>(x + (size_t)(row0 + r + 1) * ROW);
#pragma unroll
            for (int i = 0; i < VPT; ++i) vB[i] = xin[i * THREADS + t];
        }
        __builtin_amdgcn_sched_barrier(0);  // keep prefetch above select
        process_row(sh, vA, out + (size_t)(row0 + r) * ROW, t, lane, wave);

        if (r + 1 < rpb) {
            // prefetch row r+2 into bank A, then process bank B (row r+1)
            if (r + 2 < rpb) {
                const float4* __restrict__ xin =
                    reinterpret_cast<const float4*>(x + (size_t)(row0 + r + 2) * ROW);
#pragma unroll
                for (int i = 0; i < VPT; ++i) vA[i] = xin[i * THREADS + t];
            }
            __builtin_amdgcn_sched_barrier(0);
            process_row(sh, vB, out + (size_t)(row0 + r + 1) * ROW, t, lane, wave);
        }
    }
}

extern "C" void kernel_launch(void* const* d_in, const int* in_sizes, int n_in,
                              void* d_out, int out_size, void* d_ws, size_t ws_size,
                              hipStream_t stream) {
    const float* x = (const float*)d_in[0];
    float* out = (float*)d_out;
    const int rows = in_sizes[0] / ROW;   // 4096
    const int rpb  = rows / BLOCKS;       // 16 rows per persistent block
    topk_pipelined_kernel<<<BLOCKS, THREADS, 0, stream>>>(x, out, rpb);
}

// Round 5
// 340.682 us; speedup vs baseline: 1.9843x; 1.9843x over previous
//
#include <hip/hip_runtime.h>

#define TOPK    32
#define ROW     32768
#define THREADS 256
#define WAVES   4          // 256 / 64
#define F4PT    32         // float4 per thread per pass: 32 * 4 * 256 = 32768
#define BINS    2048
#define CAP     1024

__device__ __forceinline__ unsigned int f2key(float f) {
    // monotone map: larger float -> larger uint
    unsigned int u = __float_as_uint(f);
    return u ^ (0x80000000u | (unsigned int)((int)u >> 31));
}
__device__ __forceinline__ float key2f(unsigned int k) {
    unsigned int u = (k & 0x80000000u) ? (k & 0x7fffffffu) : ~k;
    return __uint_as_float(u);
}

struct Shared {
    unsigned int hist[BINS];
    unsigned int wsum[WAVES];
    unsigned int sel_g, sel_gabove;
    unsigned int sel_bin, sel_above;
    unsigned int cand_cnt;
    unsigned int cnt_s;
    float        cf[CAP];
    unsigned int cidx[CAP];
};

// Find bin B = max index with sum_{b>=B} hist[b] >= kk over BINS=2048 bins.
// Writes sh.sel_bin (=B) and sh.sel_above (= sum over bins > B).
// Requires total >= kk. Ends with __syncthreads().
__device__ __forceinline__ void hist_select(Shared& sh, int t, int lane,
                                            int wave, unsigned int kk) {
    // wave w owns bins [w*512, w*512+512), 8 bins per lane
    const int base = wave * 512 + lane * 8;
    unsigned int h[8];
    unsigned int p = 0;
#pragma unroll
    for (int j = 0; j < 8; ++j) { h[j] = sh.hist[base + j]; p += h[j]; }
    unsigned int s = p;  // suffix-inclusive sum over lanes >= lane
#pragma unroll
    for (int off = 1; off < 64; off <<= 1) {
        unsigned int vv = __shfl_down(s, off);
        if (lane + off < 64) s += vv;
    }
    if (lane == 0) sh.wsum[wave] = s;
    __syncthreads();

    if (t == 0) {
        unsigned int above = 0; int g = WAVES - 1;
        for (int w = WAVES - 1; w >= 0; --w) {
            if (above + sh.wsum[w] >= kk) { g = w; break; }
            above += sh.wsum[w];
        }
        sh.sel_g = (unsigned int)g; sh.sel_gabove = above;
    }
    __syncthreads();

    if (wave == (int)sh.sel_g) {
        unsigned int a = sh.sel_gabove + (s - p);
#pragma unroll
        for (int j = 7; j >= 0; --j) {
            unsigned int hh = h[j];
            if (a < kk && a + hh >= kk) {
                sh.sel_bin = (unsigned int)(base + j);
                sh.sel_above = a;
            }
            a += hh;
        }
    }
    __syncthreads();
}

__global__ __launch_bounds__(THREADS, 8) void topk_twopass_kernel(
    const float* __restrict__ x, float* __restrict__ out) {

    __shared__ Shared sh;
    const int row  = blockIdx.x;
    const int t    = threadIdx.x;
    const int lane = t & 63;
    const int wave = t >> 6;

    const float4* __restrict__ xin =
        reinterpret_cast<const float4*>(x + (size_t)row * ROW);
    float4* __restrict__ xout =
        reinterpret_cast<float4*>(out + (size_t)row * ROW);
    float* __restrict__ orow = out + (size_t)row * ROW;

#pragma unroll
    for (int b = 0; b < BINS / THREADS; ++b) sh.hist[t + b * THREADS] = 0;
    if (t == 0) sh.cand_cnt = 0;
    __syncthreads();

    // ---- pass 1: streaming per-thread max (no storage -> tiny reg footprint) ----
    float m = -__builtin_inff();
#pragma unroll 8
    for (int i = 0; i < F4PT; ++i) {
        float4 v = xin[i * THREADS + t];
        m = fmaxf(m, fmaxf(fmaxf(v.x, v.y), fmaxf(v.z, v.w)));
    }
    // histogram of the 256 thread-maxima (256 LDS atomics)
    atomicAdd(&sh.hist[f2key(m) >> 21], 1u);
    __syncthreads();

    hist_select(sh, t, lane, wave, TOPK);

    // L = lower edge of crossing bin: top-32 thread-maxima are 32 distinct
    // elements >= L => true 32nd-largest >= L => {x >= L} contains top-32.
    const float L = key2f(sh.sel_bin << 21);

    // ---- pass 2: re-read row (L3-resident), write masked-by-L, gather ----
#pragma unroll 4
    for (int i = 0; i < F4PT; ++i) {
        float4 v = xin[i * THREADS + t];
        float4 o;
#pragma unroll
        for (int j = 0; j < 4; ++j) {
            float f = (&v.x)[j];
            bool cand = (f >= L);
            (&o.x)[j] = cand ? f : 0.0f;
            if (cand) {
                unsigned int pos = atomicAdd(&sh.cand_cnt, 1u);
                if (pos < CAP) {
                    sh.cf[pos]   = f;
                    sh.cidx[pos] = (unsigned int)((i * THREADS + t) * 4 + j);
                }
            }
        }
        xout[i * THREADS + t] = o;
    }
    __syncthreads();  // drains vmcnt: pass-2 stores complete before fix-up
    const unsigned int C = sh.cand_cnt;

    if (C <= CAP) {
        // exact rank (value desc, idx asc); zero out the C-TOPK losers
        for (unsigned int i = t; i < C; i += THREADS) {
            float ki = sh.cf[i]; unsigned int ii = sh.cidx[i];
            unsigned int r = 0;
            for (unsigned int j = 0; j < C; ++j) {
                float kj = sh.cf[j];
                unsigned int ij = sh.cidx[j];
                r += (kj > ki || (kj == ki && ij < ii)) ? 1u : 0u;
            }
            if (r >= TOPK) orow[ii] = 0.0f;
        }
        return;
    }

    // ---- fallback (C > CAP, adversarial): exact radix select, streaming ----
    unsigned int prefix = 0; int pbits = 0;
    unsigned int kk = TOPK, e = 0;
    for (int r = 0; r < 3; ++r) {
        const int shift = (r == 0) ? 21 : (r == 1 ? 10 : 0);
        const int bits  = (r == 2) ? 10 : 11;
        const unsigned int msk = (1u << bits) - 1u;
        const int nb = 1 << bits;
        __syncthreads();
        for (int b = t; b < nb; b += THREADS) sh.hist[b] = 0;
        __syncthreads();
        for (int i = 0; i < F4PT; ++i) {
            float4 v = xin[i * THREADS + t];
#pragma unroll
            for (int j = 0; j < 4; ++j) {
                unsigned int key = f2key((&v.x)[j]);
                bool match = (pbits == 0) || ((key >> (32 - pbits)) == prefix);
                if (match) atomicAdd(&sh.hist[(key >> shift) & msk], 1u);
            }
        }
        __syncthreads();
        if (t == 0) {
            unsigned int above = 0;
            for (int b = nb - 1; b >= 0; --b) {
                unsigned int h = sh.hist[b];
                if (above + h >= kk) { sh.sel_bin = (unsigned int)b;
                                       sh.sel_above = above; break; }
                above += h;
            }
        }
        __syncthreads();
        kk = kk - sh.sel_above;
        e  = sh.hist[sh.sel_bin];
        prefix = (prefix << bits) | sh.sel_bin;
        pbits += bits;
    }
    const unsigned int T = prefix;

    unsigned int Cc = ROW;  // idx cutoff among keys == T
    if (e != kk) {
        unsigned int lo = 0, hi = ROW;
        while (hi - lo > 1u) {
            unsigned int mid = (lo + hi) >> 1;
            __syncthreads();
            if (t == 0) sh.cnt_s = 0;
            __syncthreads();
            unsigned int c = 0;
            for (int i = 0; i < F4PT; ++i) {
                float4 v = xin[i * THREADS + t];
#pragma unroll
                for (int j = 0; j < 4; ++j) {
                    unsigned int key = f2key((&v.x)[j]);
                    unsigned int idx = (unsigned int)((i * THREADS + t) * 4 + j);
                    if (key == T && idx < mid) ++c;
                }
            }
            if (c) atomicAdd(&sh.cnt_s, c);
            __syncthreads();
            if (sh.cnt_s >= kk) hi = mid; else lo = mid;
        }
        Cc = hi;
    }

    // full corrective rewrite (rare path)
    for (int i = 0; i < F4PT; ++i) {
        float4 v = xin[i * THREADS + t];
        float4 o;
#pragma unroll
        for (int j = 0; j < 4; ++j) {
            float f = (&v.x)[j];
            unsigned int key = f2key(f);
            unsigned int idx = (unsigned int)((i * THREADS + t) * 4 + j);
            (&o.x)[j] = (key > T || (key == T && idx < Cc)) ? f : 0.0f;
        }
        xout[i * THREADS + t] = o;
    }
}

extern "C" void kernel_launch(void* const* d_in, const int* in_sizes, int n_in,
                              void* d_out, int out_size, void* d_ws, size_t ws_size,
                              hipStream_t stream) {
    const float* x = (const float*)d_in[0];
    float* out = (float*)d_out;
    const int rows = in_sizes[0] / ROW;  // 4096
    topk_twopass_kernel<<<rows, THREADS, 0, stream>>>(x, out);
}

// Round 6
// 224.890 us; speedup vs baseline: 3.0060x; 1.5149x over previous
//
#include <hip/hip_runtime.h>

#define TOPK    32
#define ROW     32768
#define THREADS 512
#define WAVES   8
#define VPT     16     // float4 per thread: 16 * 4 * 512 = 32768
#define BINS    2048
#define CAP     1024

__device__ __forceinline__ unsigned int f2key(float f) {
    // monotone map: larger float -> larger uint
    unsigned int u = __float_as_uint(f);
    return u ^ (0x80000000u | (unsigned int)((int)u >> 31));
}
__device__ __forceinline__ float key2f(unsigned int k) {
    unsigned int u = (k & 0x80000000u) ? (k & 0x7fffffffu) : ~k;
    return __uint_as_float(u);
}

// LDS-only barrier: orders LDS ops across the block WITHOUT draining vmcnt,
// so the eager zero-stores (and nothing else) stay in flight through select.
__device__ __forceinline__ void bar_lds() {
    asm volatile("s_waitcnt lgkmcnt(0)" ::: "memory");
    __builtin_amdgcn_s_barrier();
}

struct Shared {
    unsigned int hist[BINS];
    unsigned int wsum[WAVES];
    unsigned int sel_g, sel_gabove;
    unsigned int sel_bin, sel_above;
    unsigned int cand_cnt;
    unsigned int cnt_s;
    float        cf[CAP];
    unsigned int cidx[CAP];
};

// Find bin B = max index with sum_{b>=B} hist[b] >= kk.
// Writes sh.sel_bin (=B) and sh.sel_above (= sum over bins > B).
// Requires total >= kk. Ends with bar_lds().
__device__ __forceinline__ void hist_select(Shared& sh, int t, int lane,
                                            int wave, unsigned int kk) {
    // stage 1: wave w owns bins [w*256, w*256+256), 4 bins/lane
    const int base = wave * 256 + lane * 4;
    unsigned int h0 = sh.hist[base + 0], h1 = sh.hist[base + 1];
    unsigned int h2 = sh.hist[base + 2], h3 = sh.hist[base + 3];
    unsigned int p = h0 + h1 + h2 + h3;
    unsigned int s = p;  // suffix-inclusive sum over lanes >= lane
#pragma unroll
    for (int off = 1; off < 64; off <<= 1) {
        unsigned int vv = __shfl_down(s, off);
        if (lane + off < 64) s += vv;
    }
    if (lane == 0) sh.wsum[wave] = s;
    bar_lds();

    // stage 2: find the wave-group containing the crossing
    if (t == 0) {
        unsigned int above = 0; int g = WAVES - 1;
        for (int w = WAVES - 1; w >= 0; --w) {
            if (above + sh.wsum[w] >= kk) { g = w; break; }
            above += sh.wsum[w];
        }
        sh.sel_g = (unsigned int)g; sh.sel_gabove = above;
    }
    bar_lds();

    // stage 3: the owning wave (still holds h0..h3, p, s) finds the bin
    if (wave == (int)sh.sel_g) {
        unsigned int a = sh.sel_gabove + (s - p);
        unsigned int hh[4] = {h0, h1, h2, h3};
#pragma unroll
        for (int j = 3; j >= 0; --j) {
            unsigned int h = hh[j];
            if (a < kk && a + h >= kk) {
                sh.sel_bin = (unsigned int)(base + j);
                sh.sel_above = a;
            }
            a += h;
        }
    }
    bar_lds();
}

__global__ __launch_bounds__(THREADS, 4) void topk_eager_kernel(
    const float* __restrict__ x, float* __restrict__ out) {

    __shared__ Shared sh;
    const int row  = blockIdx.x;
    const int t    = threadIdx.x;
    const int lane = t & 63;
    const int wave = t >> 6;

    const float4* __restrict__ xin =
        reinterpret_cast<const float4*>(x + (size_t)row * ROW);
    float4* __restrict__ xout =
        reinterpret_cast<float4*>(out + (size_t)row * ROW);
    float* __restrict__ orow = out + (size_t)row * ROW;

    // Load row into registers AND eagerly store zeros over the whole output
    // row. The zero-stores depend on nothing -> they issue interleaved with
    // the loads and drain during select. Winners are scattered at the end.
    float4 v[VPT];
    const float4 z4 = make_float4(0.f, 0.f, 0.f, 0.f);
#pragma unroll
    for (int i = 0; i < VPT; ++i) {
        v[i] = xin[i * THREADS + t];
        xout[i * THREADS + t] = z4;
    }
    __builtin_amdgcn_sched_barrier(0);  // don't sink loads/stores below select

    // zero hist + counters (LDS)
#pragma unroll
    for (int b = 0; b < BINS / THREADS; ++b) sh.hist[t + b * THREADS] = 0;
    if (t == 0) sh.cand_cnt = 0;

    // per-thread max (waits only on this thread's loads)
    float m = -__builtin_inff();
#pragma unroll
    for (int i = 0; i < VPT; ++i)
        m = fmaxf(m, fmaxf(fmaxf(v[i].x, v[i].y), fmaxf(v[i].z, v[i].w)));

    bar_lds();
    // histogram of the 512 thread-maxima (512 LDS atomics)
    atomicAdd(&sh.hist[f2key(m) >> 21], 1u);
    bar_lds();

    hist_select(sh, t, lane, wave, TOPK);

    // L = lower edge of crossing bin: the top-32 thread-maxima are 32
    // distinct elements >= L => true 32nd-largest >= L => {x >= L} holds
    // the full top-32 (and C >= 32).
    const float L = key2f(sh.sel_bin << 21);

    // gather candidates from registers
#pragma unroll
    for (int i = 0; i < VPT; ++i) {
#pragma unroll
        for (int j = 0; j < 4; ++j) {
            float f = (&v[i].x)[j];
            if (f >= L) {
                unsigned int pos = atomicAdd(&sh.cand_cnt, 1u);
                if (pos < CAP) {
                    sh.cf[pos]   = f;
                    sh.cidx[pos] = (unsigned int)((i * THREADS + t) * 4 + j);
                }
            }
        }
    }
    bar_lds();
    const unsigned int C = sh.cand_cnt;

    if (C <= CAP) {
        // exact rank (value desc, idx asc); winners -> registers
        float        wv[2];
        unsigned int wi[2];
        int nw = 0;
        for (unsigned int i = t; i < C; i += THREADS) {
            float ki = sh.cf[i]; unsigned int ii = sh.cidx[i];
            unsigned int r = 0;
            for (unsigned int j = 0; j < C; ++j) {
                float kj = sh.cf[j];
                unsigned int ij = sh.cidx[j];
                r += (kj > ki || (kj == ki && ij < ii)) ? 1u : 0u;
            }
            if (r < TOPK) { wv[nw] = ki; wi[nw] = ii; ++nw; }
        }
        // Full barrier WITH vmcnt drain: every wave's zero-stores are retired
        // before any winner store to the same addresses.
        __syncthreads();
        for (int q = 0; q < nw; ++q) orow[wi[q]] = wv[q];
        return;
    }

    // ---- fallback (C > CAP, adversarial data): exact radix select ----
    unsigned int prefix = 0; int pbits = 0;
    unsigned int kk = TOPK, e = 0;
    for (int r = 0; r < 3; ++r) {
        const int shift = (r == 0) ? 21 : (r == 1 ? 10 : 0);
        const int bits  = (r == 2) ? 10 : 11;
        const unsigned int msk = (1u << bits) - 1u;
        bar_lds();  // protect prior hist reads before re-zeroing
#pragma unroll
        for (int b = 0; b < BINS / THREADS; ++b) sh.hist[t + b * THREADS] = 0;
        bar_lds();
#pragma unroll
        for (int i = 0; i < VPT; ++i) {
#pragma unroll
            for (int j = 0; j < 4; ++j) {
                unsigned int key = f2key((&v[i].x)[j]);
                bool match = (pbits == 0) || ((key >> (32 - pbits)) == prefix);
                if (match) atomicAdd(&sh.hist[(key >> shift) & msk], 1u);
            }
        }
        bar_lds();
        hist_select(sh, t, lane, wave, kk);
        kk = kk - sh.sel_above;
        e  = sh.hist[sh.sel_bin];
        prefix = (prefix << bits) | sh.sel_bin;
        pbits += bits;
    }
    const unsigned int T = prefix;

    unsigned int Cc = ROW;  // idx cutoff among keys == T
    if (e != kk) {
        unsigned int lo = 0, hi = ROW;
        while (hi - lo > 1u) {
            unsigned int mid = (lo + hi) >> 1;
            bar_lds();
            if (t == 0) sh.cnt_s = 0;
            bar_lds();
            unsigned int c = 0;
#pragma unroll
            for (int i = 0; i < VPT; ++i) {
#pragma unroll
                for (int j = 0; j < 4; ++j) {
                    unsigned int key = f2key((&v[i].x)[j]);
                    unsigned int idx = (unsigned int)((i * THREADS + t) * 4 + j);
                    if (key == T && idx < mid) ++c;
                }
            }
            if (c) atomicAdd(&sh.cnt_s, c);
            bar_lds();
            if (sh.cnt_s >= kk) hi = mid; else lo = mid;
        }
        Cc = hi;
    }

    // full corrective rewrite; drain zero-stores first (same-address stores)
    __syncthreads();
#pragma unroll
    for (int i = 0; i < VPT; ++i) {
        float4 o;
#pragma unroll
        for (int j = 0; j < 4; ++j) {
            float f = (&v[i].x)[j];
            unsigned int key = f2key(f);
            unsigned int idx = (unsigned int)((i * THREADS + t) * 4 + j);
            (&o.x)[j] = (key > T || (key == T && idx < Cc)) ? f : 0.0f;
        }
        xout[i * THREADS + t] = o;
    }
}

extern "C" void kernel_launch(void* const* d_in, const int* in_sizes, int n_in,
                              void* d_out, int out_size, void* d_ws, size_t ws_size,
                              hipStream_t stream) {
    const float* x = (const float*)d_in[0];
    float* out = (float*)d_out;
    const int rows = in_sizes[0] / ROW;  // 4096
    topk_eager_kernel<<<rows, THREADS, 0, stream>>>(x, out);
}